// Round 11
// baseline (589.151 us; speedup 1.0000x reference)
//
#include <hip/hip_runtime.h>
#include <hip/hip_bf16.h>
#include <hip/hip_fp16.h>

#define EPSBN 1e-5f
#define BSHIFT 7                  // 128 nodes per bucket; pack = (src<<7)|dst_local
#define BMASK  ((1 << BSHIFT) - 1)
#define CHUNK  4096               // edges per k_bin block
#define DCAP   12288              // stash cap per bucket

typedef int iv4 __attribute__((ext_vector_type(4)));

static __host__ __device__ inline size_t alignup(size_t x) { return (x + 255) & ~(size_t)255; }

__device__ inline float2 h2f(unsigned int b) {
    __half2 h = *reinterpret_cast<__half2*>(&b);
    return __half22float2(h);
}

// ---------------- build step 1: bucket counts (LDS-aggregated) ----------------

__global__ __launch_bounds__(256) void k_bcount(const int* __restrict__ dst, int* __restrict__ bcnt,
                                                int E, int N, int nbuck) {
    __shared__ int h[1024];
    for (int i = threadIdx.x; i < nbuck; i += 256) h[i] = 0;
    __syncthreads();
    int ng = E >> 2;
    const iv4* dst4 = reinterpret_cast<const iv4*>(dst);
    for (int g = blockIdx.x * 256 + threadIdx.x; g < ng; g += gridDim.x * 256) {
        iv4 d = __builtin_nontemporal_load(dst4 + g);
        if ((unsigned)d.x < (unsigned)N) atomicAdd(&h[d.x >> BSHIFT], 1);
        if ((unsigned)d.y < (unsigned)N) atomicAdd(&h[d.y >> BSHIFT], 1);
        if ((unsigned)d.z < (unsigned)N) atomicAdd(&h[d.z >> BSHIFT], 1);
        if ((unsigned)d.w < (unsigned)N) atomicAdd(&h[d.w >> BSHIFT], 1);
    }
    if (blockIdx.x == 0 && threadIdx.x == 0) {
        for (int k = ng * 4; k < E; ++k) {
            int d = dst[k];
            if ((unsigned)d < (unsigned)N) atomicAdd(&h[d >> BSHIFT], 1);
        }
    }
    __syncthreads();
    for (int i = threadIdx.x; i < nbuck; i += 256) {
        int c = h[i];
        if (c) atomicAdd(&bcnt[i], c);
    }
}

// ---------------- build step 2: scan buckets ----------------

__global__ void k_bscan(const int* __restrict__ bcnt, int* __restrict__ bbase, int* __restrict__ bcur,
                        int* __restrict__ row_off, int nbuck, int N) {
    if (threadIdx.x == 0 && blockIdx.x == 0) {
        int run = 0;
        for (int i = 0; i < nbuck; ++i) { bbase[i] = run; bcur[i] = run; run += bcnt[i]; }
        row_off[N] = run;
    }
}

// ---------------- build step 3: bin packed (src,dst_local) into bucket regions ----------------

__global__ __launch_bounds__(256) void k_bin(const int* __restrict__ src, const int* __restrict__ dst,
                                             int* __restrict__ bcur, int* __restrict__ csrbuf,
                                             int E, int N, int nbuck) {
    __shared__ int sd[CHUNK], ss[CHUNK];
    __shared__ int gb[1024], lc[1024];
    int e0 = blockIdx.x * CHUNK;
    for (int i = threadIdx.x; i < nbuck; i += 256) lc[i] = 0;
    __syncthreads();
    const iv4* dst4 = reinterpret_cast<const iv4*>(dst);
    const iv4* src4 = reinterpret_cast<const iv4*>(src);
#pragma unroll
    for (int k = 0; k < 4; ++k) {
        int l = k * 256 + threadIdx.x;
        int g = (e0 >> 2) + l;
        int ebase = g * 4;
        if (ebase + 3 < E) {
            iv4 d = __builtin_nontemporal_load(dst4 + g);
            iv4 s = __builtin_nontemporal_load(src4 + g);
            int dd[4] = {d.x, d.y, d.z, d.w};
            int sv[4] = {s.x, s.y, s.z, s.w};
#pragma unroll
            for (int j = 0; j < 4; ++j) {
                int dj = dd[j];
                if ((unsigned)dj < (unsigned)N) {
                    sd[l * 4 + j] = dj; ss[l * 4 + j] = sv[j];
                    atomicAdd(&lc[dj >> BSHIFT], 1);
                } else sd[l * 4 + j] = -1;
            }
        } else {
#pragma unroll
            for (int j = 0; j < 4; ++j) {
                int e = ebase + j;
                if (e < E) {
                    int dj = dst[e];
                    if ((unsigned)dj < (unsigned)N) {
                        sd[l * 4 + j] = dj; ss[l * 4 + j] = src[e];
                        atomicAdd(&lc[dj >> BSHIFT], 1);
                    } else sd[l * 4 + j] = -1;
                } else sd[l * 4 + j] = -1;
            }
        }
    }
    __syncthreads();
    for (int i = threadIdx.x; i < nbuck; i += 256) {
        int c = lc[i];
        gb[i] = c ? atomicAdd(&bcur[i], c) : 0;
        lc[i] = 0;
    }
    __syncthreads();
#pragma unroll
    for (int k = 0; k < 4; ++k) {
        int l = k * 256 + threadIdx.x;
#pragma unroll
        for (int j = 0; j < 4; ++j) {
            int dj = sd[l * 4 + j];
            if (dj >= 0) {
                int b = dj >> BSHIFT;
                int idx = atomicAdd(&lc[b], 1);
                csrbuf[gb[b] + idx] = (ss[l * 4 + j] << BSHIFT) | (dj & BMASK);
            }
        }
    }
}

// ---------------- build step 4: per-bucket scatter with src-half segmentation ----------------
// Row layout: [row_off[v], row_mid[v]) = srcs < NH ; [row_mid[v], row_off[v+1]) = srcs >= NH.

__global__ __launch_bounds__(256) void k_bucket(int* __restrict__ csrbuf, const int* __restrict__ bbase,
                                                const int* __restrict__ bcnt, int* __restrict__ row_off,
                                                int* __restrict__ row_mid, float* __restrict__ dinv,
                                                int N, int NH) {
    __shared__ int stash[DCAP];
    __shared__ int h[128], hlo[128], off[128], curlo[128], curhi[128];
    int b = blockIdx.x;
    int rbase = bbase[b];
    int rs = bcnt[b]; if (rs > DCAP) rs = DCAP;
    int d0 = b << BSHIFT;
    int nloc = min(128, N - d0);
    if (threadIdx.x < 128) { h[threadIdx.x] = 0; hlo[threadIdx.x] = 0; }
    for (int i = threadIdx.x; i < rs; i += 256) stash[i] = csrbuf[rbase + i];
    __syncthreads();
    for (int i = threadIdx.x; i < rs; i += 256) {
        int v = stash[i];
        int dl = v & BMASK;
        atomicAdd(&h[dl], 1);
        if ((v >> BSHIFT) < NH) atomicAdd(&hlo[dl], 1);
    }
    __syncthreads();
    if (threadIdx.x < 128) off[threadIdx.x] = h[threadIdx.x];
    __syncthreads();
    for (int o = 1; o < 128; o <<= 1) {
        int t = 0;
        if (threadIdx.x < 128 && (int)threadIdx.x >= o) t = off[threadIdx.x - o];
        __syncthreads();
        if (threadIdx.x < 128) off[threadIdx.x] += t;
        __syncthreads();
    }
    if (threadIdx.x < 128) {
        int ex = off[threadIdx.x] - h[threadIdx.x];   // exclusive prefix
        curlo[threadIdx.x] = ex;
        curhi[threadIdx.x] = ex + hlo[threadIdx.x];
        if ((int)threadIdx.x < nloc) {
            row_off[d0 + threadIdx.x] = rbase + ex;
            row_mid[d0 + threadIdx.x] = rbase + ex + hlo[threadIdx.x];
            dinv[d0 + threadIdx.x] = rsqrtf((float)(h[threadIdx.x] + 1));  // +1 self-loop
        }
    }
    __syncthreads();
    for (int i = threadIdx.x; i < rs; i += 256) {
        int v = stash[i];
        int dl = v & BMASK;
        int s = v >> BSHIFT;
        int p = (s < NH) ? atomicAdd(&curlo[dl], 1) : atomicAdd(&curhi[dl], 1);
        csrbuf[rbase + p] = s;
    }
}

// xs_h[v] = fp16( dinv[v] * x[v] ), padded to 8 halves = 16 B/row
__global__ __launch_bounds__(256) void k_xs(const float* __restrict__ x, const float* __restrict__ dinv,
                                            uint4* __restrict__ xs_h, int N) {
    int v = blockIdx.x * blockDim.x + threadIdx.x;
    if (v < N) {
        float w = dinv[v];
        const float* xp = x + (size_t)v * 5;
        __half hs[8];
#pragma unroll
        for (int k = 0; k < 5; ++k) hs[k] = __float2half(w * xp[k]);
        hs[5] = hs[6] = hs[7] = __float2half(0.f);
        xs_h[v] = *reinterpret_cast<uint4*>(hs);
    }
}

// ---------------- Layer 1: one 16B fp16 row per edge per lane; matmul 5->32; BN1 stats ----------------

__global__ __launch_bounds__(256) void k_agg1(const uint4* __restrict__ xs_h, const int* __restrict__ csr,
                                              const int* __restrict__ row_off, const float* __restrict__ dinv,
                                              const float* __restrict__ W1, const float* __restrict__ b1,
                                              float* __restrict__ out, float* __restrict__ sum, float* __restrict__ sq,
                                              int N) {
    __shared__ float lss[256], lsq[256];
    int lane = threadIdx.x & 63;
    int wave = (blockIdx.x * blockDim.x + threadIdx.x) >> 6;
    int nw = (gridDim.x * blockDim.x) >> 6;
    int c = lane & 31;
    float w0 = W1[c], w1 = W1[32 + c], w2 = W1[64 + c], w3 = W1[96 + c], w4 = W1[128 + c];
    float bc = b1[c];
    float ls = 0.f, lq = 0.f;
    for (int v = wave; v < N; v += nw) {
        int s0 = row_off[v], s1 = row_off[v + 1];
        float a0 = 0, a1 = 0, a2 = 0, a3 = 0, a4 = 0;
        int e = s0 + lane;
        for (; e + 64 < s1; e += 128) {
            uint4 ua = xs_h[csr[e]];
            uint4 ub = xs_h[csr[e + 64]];
            float2 f;
            f = h2f(ua.x); a0 += f.x; a1 += f.y;
            f = h2f(ua.y); a2 += f.x; a3 += f.y;
            f = h2f(ua.z); a4 += f.x;
            f = h2f(ub.x); a0 += f.x; a1 += f.y;
            f = h2f(ub.y); a2 += f.x; a3 += f.y;
            f = h2f(ub.z); a4 += f.x;
        }
        if (e < s1) {
            uint4 ua = xs_h[csr[e]];
            float2 f;
            f = h2f(ua.x); a0 += f.x; a1 += f.y;
            f = h2f(ua.y); a2 += f.x; a3 += f.y;
            f = h2f(ua.z); a4 += f.x;
        }
#pragma unroll
        for (int off = 32; off >= 1; off >>= 1) {
            a0 += __shfl_xor(a0, off);
            a1 += __shfl_xor(a1, off);
            a2 += __shfl_xor(a2, off);
            a3 += __shfl_xor(a3, off);
            a4 += __shfl_xor(a4, off);
        }
        if (lane < 32) {
            float dv = dinv[v];
            uint4 uv = xs_h[v];
            float2 f0 = h2f(uv.x), f1 = h2f(uv.y), f2v = h2f(uv.z);
            float t0 = dv * (a0 + f0.x);
            float t1 = dv * (a1 + f0.y);
            float t2 = dv * (a2 + f1.x);
            float t3 = dv * (a3 + f1.y);
            float t4 = dv * (a4 + f2v.x);
            float h = bc;
            h = fmaf(t0, w0, h); h = fmaf(t1, w1, h); h = fmaf(t2, w2, h);
            h = fmaf(t3, w3, h); h = fmaf(t4, w4, h);
            out[(size_t)v * 32 + c] = h;
            ls += h; lq += h * h;
        }
    }
    lss[threadIdx.x] = ls; lsq[threadIdx.x] = lq;
    __syncthreads();
    if (threadIdx.x < 32) {
        float s = 0.f, q = 0.f;
#pragma unroll
        for (int j = 0; j < 8; ++j) { s += lss[threadIdx.x + 32 * j]; q += lsq[threadIdx.x + 32 * j]; }
        atomicAdd(&sum[threadIdx.x], s);
        atomicAdd(&sq[threadIdx.x], q);
    }
}

// ---------------- BN params ----------------

__global__ void k_bnparam(const float* __restrict__ sum, const float* __restrict__ sq,
                          const float* __restrict__ gamma, const float* __restrict__ beta,
                          float* __restrict__ aOut, float* __restrict__ dOut, float invN) {
    int c = threadIdx.x;
    if (c < 32) {
        float mean = sum[c] * invN;
        float var = fmaxf(sq[c] * invN - mean * mean, 0.f);
        float rinv = rsqrtf(var + EPSBN);
        float a = gamma[c] * rinv;
        aOut[c] = a;
        dOut[c] = beta[c] - mean * a;
    }
}

// ---------------- h2h = fp16( dinv[v] * (relu(bn1(bufIn)) @ W2) ) ----------------

__global__ __launch_bounds__(256) void k_h2(const float* __restrict__ bufIn, const float* __restrict__ W2,
                                            const float* __restrict__ a1, const float* __restrict__ d1,
                                            const float* __restrict__ dinv, __half* __restrict__ h2h, int N) {
    __shared__ float W2s[1024];
    __shared__ float rbuf[8][33];
    for (int i = threadIdx.x; i < 1024; i += 256) W2s[i] = W2[i];
    int g = threadIdx.x >> 5, c = threadIdx.x & 31;
    int v = blockIdx.x * 8 + g;
    float r = 0.f;
    if (v < N) {
        float val = bufIn[(size_t)v * 32 + c];
        r = fmaxf(fmaf(a1[c], val, d1[c]), 0.f);
    }
    __syncthreads();
    rbuf[g][c] = r;
    __syncthreads();
    if (v < N) {
        float h = 0.f;
#pragma unroll
        for (int k = 0; k < 32; ++k) h = fmaf(rbuf[g][k], W2s[k * 32 + c], h);
        h2h[(size_t)v * 32 + c] = __float2half(h * dinv[v]);
    }
}

// ---------------- Layer 2: two-phase gather (src<NH then src>=NH) for L2 residence ----------------

__global__ __launch_bounds__(256) void k_agg2(const uint4* __restrict__ h2h4, const int* __restrict__ csr,
                                              const int* __restrict__ row_off, const int* __restrict__ row_mid,
                                              const float* __restrict__ dinv, const float* __restrict__ b2,
                                              float* out, float* __restrict__ sum, float* __restrict__ sq, int N) {
    __shared__ float lssum[128], lssq[128];
    int lane = threadIdx.x & 63;
    int g = lane >> 2;       // 16 groups, one row each per iter
    int q = lane & 3;        // 16B slot: channels q*8 .. q*8+7
    int wave = (blockIdx.x * blockDim.x + threadIdx.x) >> 6;
    int nw = (gridDim.x * blockDim.x) >> 6;
    float bcv[8];
#pragma unroll
    for (int j = 0; j < 8; ++j) bcv[j] = b2[q * 8 + j];
    float ls[8], lq[8];
#pragma unroll
    for (int j = 0; j < 8; ++j) { ls[j] = 0.f; lq[j] = 0.f; }
    for (int pass = 0; pass < 2; ++pass) {
        for (int v = wave; v < N; v += nw) {
            int s0 = pass ? row_mid[v] : row_off[v];
            int s1 = pass ? row_off[v + 1] : row_mid[v];
            float acc[8];
#pragma unroll
            for (int j = 0; j < 8; ++j) acc[j] = 0.f;
            int e = s0 + g;
            for (; e + 16 < s1; e += 32) {
                int sA = csr[e], sB = csr[e + 16];
                uint4 ua = h2h4[(size_t)sA * 4 + q];
                uint4 ub = h2h4[(size_t)sB * 4 + q];
                float2 f;
                f = h2f(ua.x); acc[0] += f.x; acc[1] += f.y;
                f = h2f(ua.y); acc[2] += f.x; acc[3] += f.y;
                f = h2f(ua.z); acc[4] += f.x; acc[5] += f.y;
                f = h2f(ua.w); acc[6] += f.x; acc[7] += f.y;
                f = h2f(ub.x); acc[0] += f.x; acc[1] += f.y;
                f = h2f(ub.y); acc[2] += f.x; acc[3] += f.y;
                f = h2f(ub.z); acc[4] += f.x; acc[5] += f.y;
                f = h2f(ub.w); acc[6] += f.x; acc[7] += f.y;
            }
            if (e < s1) {
                uint4 ua = h2h4[(size_t)csr[e] * 4 + q];
                float2 f;
                f = h2f(ua.x); acc[0] += f.x; acc[1] += f.y;
                f = h2f(ua.y); acc[2] += f.x; acc[3] += f.y;
                f = h2f(ua.z); acc[4] += f.x; acc[5] += f.y;
                f = h2f(ua.w); acc[6] += f.x; acc[7] += f.y;
            }
#pragma unroll
            for (int off = 4; off <= 32; off <<= 1) {
#pragma unroll
                for (int j = 0; j < 8; ++j) acc[j] += __shfl_xor(acc[j], off);
            }
            if (lane < 4) {
                float* op = out + (size_t)v * 32 + q * 8;
                if (pass == 0) {
                    float4 p0 = {acc[0], acc[1], acc[2], acc[3]};
                    float4 p1 = {acc[4], acc[5], acc[6], acc[7]};
                    *reinterpret_cast<float4*>(op) = p0;          // raw partial
                    *reinterpret_cast<float4*>(op + 4) = p1;
                } else {
                    float dv = dinv[v];
                    uint4 uv = h2h4[(size_t)v * 4 + q];   // already dinv[v]*h2
                    float hv[8];
                    float2 f;
                    f = h2f(uv.x); hv[0] = f.x; hv[1] = f.y;
                    f = h2f(uv.y); hv[2] = f.x; hv[3] = f.y;
                    f = h2f(uv.z); hv[4] = f.x; hv[5] = f.y;
                    f = h2f(uv.w); hv[6] = f.x; hv[7] = f.y;
                    float4 p0 = *reinterpret_cast<const float4*>(op);
                    float4 p1 = *reinterpret_cast<const float4*>(op + 4);
                    float part[8] = {p0.x, p0.y, p0.z, p0.w, p1.x, p1.y, p1.z, p1.w};
                    float o[8];
#pragma unroll
                    for (int j = 0; j < 8; ++j) {
                        o[j] = fmaf(dv, acc[j] + part[j] + hv[j], bcv[j]);
                        ls[j] += o[j]; lq[j] += o[j] * o[j];
                    }
                    float4 o0 = {o[0], o[1], o[2], o[3]};
                    float4 o1 = {o[4], o[5], o[6], o[7]};
                    *reinterpret_cast<float4*>(op) = o0;
                    *reinterpret_cast<float4*>(op + 4) = o1;
                }
            }
        }
    }
    int wib = threadIdx.x >> 6;
    if (lane < 4) {
#pragma unroll
        for (int j = 0; j < 8; ++j) {
            lssum[wib * 32 + q * 8 + j] = ls[j];
            lssq[wib * 32 + q * 8 + j] = lq[j];
        }
    }
    __syncthreads();
    if (threadIdx.x < 32) {
        float s = lssum[threadIdx.x] + lssum[32 + threadIdx.x] + lssum[64 + threadIdx.x] + lssum[96 + threadIdx.x];
        float t = lssq[threadIdx.x] + lssq[32 + threadIdx.x] + lssq[64 + threadIdx.x] + lssq[96 + threadIdx.x];
        atomicAdd(&sum[threadIdx.x], s);
        atomicAdd(&sq[threadIdx.x], t);
    }
}

// ---------------- p[v] = dinv[v] * (relu(bn2(buf[v])) @ W3) ----------------

__global__ __launch_bounds__(256) void k_h3p(const float* __restrict__ buf, const float* __restrict__ a2,
                                             const float* __restrict__ d2, const float* __restrict__ W3,
                                             const float* __restrict__ dinv, float* __restrict__ p, int N) {
    int c = threadIdx.x & 31;
    int v = blockIdx.x * 8 + (threadIdx.x >> 5);
    if (v >= N) return;
    float val = buf[(size_t)v * 32 + c];
    float r = fmaxf(fmaf(a2[c], val, d2[c]), 0.f) * W3[c];
#pragma unroll
    for (int off = 16; off >= 1; off >>= 1) r += __shfl_xor(r, off, 32);
    if (c == 0) p[v] = dinv[v] * r;
}

// ---------------- Layer 3: scalar gather-reduce ----------------

__global__ __launch_bounds__(256) void k_agg3(const float* __restrict__ p, const int* __restrict__ csr,
                                              const int* __restrict__ row_off, const float* __restrict__ dinv,
                                              const float* __restrict__ b3, float* __restrict__ out, int N) {
    int lane = threadIdx.x & 63;
    int wave = (blockIdx.x * blockDim.x + threadIdx.x) >> 6;
    int nw = (gridDim.x * blockDim.x) >> 6;
    for (int v = wave; v < N; v += nw) {
        int s0 = row_off[v], s1 = row_off[v + 1];
        float acc = 0.f;
        int e = s0 + lane;
        for (; e + 64 < s1; e += 128) acc += p[csr[e]] + p[csr[e + 64]];
        if (e < s1) acc += p[csr[e]];
#pragma unroll
        for (int off = 32; off >= 1; off >>= 1) acc += __shfl_xor(acc, off);
        if (lane == 0) out[v] = fmaf(dinv[v], acc + p[v], b3[0]);
    }
}

// ---------------- launch ----------------

extern "C" void kernel_launch(void* const* d_in, const int* in_sizes, int n_in,
                              void* d_out, int out_size, void* d_ws, size_t ws_size,
                              hipStream_t stream) {
    const float* x      = (const float*)d_in[0];
    const int*   ei     = (const int*)d_in[1];
    const float* W1     = (const float*)d_in[2];
    const float* b1     = (const float*)d_in[3];
    const float* gamma1 = (const float*)d_in[4];
    const float* beta1  = (const float*)d_in[5];
    const float* W2     = (const float*)d_in[6];
    const float* b2     = (const float*)d_in[7];
    const float* gamma2 = (const float*)d_in[8];
    const float* beta2  = (const float*)d_in[9];
    const float* W3     = (const float*)d_in[10];
    const float* b3     = (const float*)d_in[11];

    int N = out_size;             // 100000 nodes (<= 131072 for LDS hists)
    int E = in_sizes[1] / 2;      // 6400000 edges
    const int* srcp = ei;
    const int* dstp = ei + E;
    int nbuck = (N + BMASK) >> BSHIFT;   // 782
    int NH = N / 2;

    char* w = (char*)d_ws;
    int*    csr     = (int*)w;         w += alignup((size_t)E * 4);     // doubles as packed-pair buffer
    int*    row_off = (int*)w;         w += alignup((size_t)(N + 1) * 4);
    int*    row_mid = (int*)w;         w += alignup((size_t)N * 4);
    float*  dinv    = (float*)w;       w += alignup((size_t)N * 4);
    uint4*  xs_h    = (uint4*)w;       w += alignup((size_t)N * 16);
    __half* h2h     = (__half*)w;      w += alignup((size_t)N * 32 * 2);
    float*  buf     = (float*)w;       w += alignup((size_t)N * 32 * 4);
    float*  pbuf    = (float*)w;       w += alignup((size_t)N * 4);
    float*  stats   = (float*)w;       w += alignup(256 * 4);
    int*    bcnt    = (int*)w;         w += alignup(1024 * 4);
    int*    bbase   = (int*)w;         w += alignup(1024 * 4);
    int*    bcur    = (int*)w;         w += alignup(1024 * 4);

    float* sum1 = stats, *sq1 = stats + 32, *sum2 = stats + 64, *sq2 = stats + 96;
    float* a1 = stats + 128, *d1 = stats + 160, *a2 = stats + 192, *d2 = stats + 224;

    (void)hipMemsetAsync(bcnt, 0, 1024 * 4, stream);
    (void)hipMemsetAsync(stats, 0, 128 * 4, stream);

    k_bcount<<<1024, 256, 0, stream>>>(dstp, bcnt, E, N, nbuck);
    k_bscan<<<1, 64, 0, stream>>>(bcnt, bbase, bcur, row_off, nbuck, N);
    k_bin<<<(E + CHUNK - 1) / CHUNK, 256, 0, stream>>>(srcp, dstp, bcur, csr, E, N, nbuck);
    k_bucket<<<nbuck, 256, 0, stream>>>(csr, bbase, bcnt, row_off, row_mid, dinv, N, NH);
    k_xs<<<(N + 255) / 256, 256, 0, stream>>>(x, dinv, xs_h, N);

    float invN = 1.0f / (float)N;

    k_agg1<<<2048, 256, 0, stream>>>(xs_h, csr, row_off, dinv, W1, b1, buf, sum1, sq1, N);
    k_bnparam<<<1, 32, 0, stream>>>(sum1, sq1, gamma1, beta1, a1, d1, invN);
    k_h2<<<(N + 7) / 8, 256, 0, stream>>>(buf, W2, a1, d1, dinv, h2h, N);
    k_agg2<<<2048, 256, 0, stream>>>((const uint4*)h2h, csr, row_off, row_mid, dinv, b2, buf, sum2, sq2, N);
    k_bnparam<<<1, 32, 0, stream>>>(sum2, sq2, gamma2, beta2, a2, d2, invN);
    k_h3p<<<(N + 7) / 8, 256, 0, stream>>>(buf, a2, d2, W3, dinv, pbuf, N);
    k_agg3<<<2048, 256, 0, stream>>>(pbuf, csr, row_off, dinv, b3, (float*)d_out, N);
}

// Round 12
// 560.518 us; speedup vs baseline: 1.0511x; 1.0511x over previous
//
#include <hip/hip_runtime.h>
#include <hip/hip_bf16.h>
#include <hip/hip_fp16.h>

#define EPSBN 1e-5f
#define BSHIFT 7                  // 128 nodes per bucket; pack = (src<<7)|dst_local
#define BMASK  ((1 << BSHIFT) - 1)
#define CHUNK  4096               // edges per k_bin block
#define DCAP   12288              // stash cap per bucket

typedef int iv4 __attribute__((ext_vector_type(4)));

static __host__ __device__ inline size_t alignup(size_t x) { return (x + 255) & ~(size_t)255; }

__device__ inline float2 h2f(unsigned int b) {
    __half2 h = *reinterpret_cast<__half2*>(&b);
    return __half22float2(h);
}

__device__ inline void acc8(float* acc, uint4 u) {
    float2 f;
    f = h2f(u.x); acc[0] += f.x; acc[1] += f.y;
    f = h2f(u.y); acc[2] += f.x; acc[3] += f.y;
    f = h2f(u.z); acc[4] += f.x; acc[5] += f.y;
    f = h2f(u.w); acc[6] += f.x; acc[7] += f.y;
}

// ---------------- build step 1: bucket counts (LDS-aggregated) ----------------

__global__ __launch_bounds__(256) void k_bcount(const int* __restrict__ dst, int* __restrict__ bcnt,
                                                int E, int N, int nbuck) {
    __shared__ int h[1024];
    for (int i = threadIdx.x; i < nbuck; i += 256) h[i] = 0;
    __syncthreads();
    int ng = E >> 2;
    const iv4* dst4 = reinterpret_cast<const iv4*>(dst);
    for (int g = blockIdx.x * 256 + threadIdx.x; g < ng; g += gridDim.x * 256) {
        iv4 d = __builtin_nontemporal_load(dst4 + g);
        if ((unsigned)d.x < (unsigned)N) atomicAdd(&h[d.x >> BSHIFT], 1);
        if ((unsigned)d.y < (unsigned)N) atomicAdd(&h[d.y >> BSHIFT], 1);
        if ((unsigned)d.z < (unsigned)N) atomicAdd(&h[d.z >> BSHIFT], 1);
        if ((unsigned)d.w < (unsigned)N) atomicAdd(&h[d.w >> BSHIFT], 1);
    }
    if (blockIdx.x == 0 && threadIdx.x == 0) {
        for (int k = ng * 4; k < E; ++k) {
            int d = dst[k];
            if ((unsigned)d < (unsigned)N) atomicAdd(&h[d >> BSHIFT], 1);
        }
    }
    __syncthreads();
    for (int i = threadIdx.x; i < nbuck; i += 256) {
        int c = h[i];
        if (c) atomicAdd(&bcnt[i], c);
    }
}

// ---------------- build step 2: scan buckets ----------------

__global__ void k_bscan(const int* __restrict__ bcnt, int* __restrict__ bbase, int* __restrict__ bcur,
                        int* __restrict__ row_off, int nbuck, int N) {
    if (threadIdx.x == 0 && blockIdx.x == 0) {
        int run = 0;
        for (int i = 0; i < nbuck; ++i) { bbase[i] = run; bcur[i] = run; run += bcnt[i]; }
        row_off[N] = run;
    }
}

// ---------------- build step 3: bin packed (src,dst_local) into bucket regions ----------------

__global__ __launch_bounds__(256) void k_bin(const int* __restrict__ src, const int* __restrict__ dst,
                                             int* __restrict__ bcur, int* __restrict__ csrbuf,
                                             int E, int N, int nbuck) {
    __shared__ int sd[CHUNK], ss[CHUNK];
    __shared__ int gb[1024], lc[1024];
    int e0 = blockIdx.x * CHUNK;
    for (int i = threadIdx.x; i < nbuck; i += 256) lc[i] = 0;
    __syncthreads();
    const iv4* dst4 = reinterpret_cast<const iv4*>(dst);
    const iv4* src4 = reinterpret_cast<const iv4*>(src);
#pragma unroll
    for (int k = 0; k < 4; ++k) {
        int l = k * 256 + threadIdx.x;
        int g = (e0 >> 2) + l;
        int ebase = g * 4;
        if (ebase + 3 < E) {
            iv4 d = __builtin_nontemporal_load(dst4 + g);
            iv4 s = __builtin_nontemporal_load(src4 + g);
            int dd[4] = {d.x, d.y, d.z, d.w};
            int sv[4] = {s.x, s.y, s.z, s.w};
#pragma unroll
            for (int j = 0; j < 4; ++j) {
                int dj = dd[j];
                if ((unsigned)dj < (unsigned)N) {
                    sd[l * 4 + j] = dj; ss[l * 4 + j] = sv[j];
                    atomicAdd(&lc[dj >> BSHIFT], 1);
                } else sd[l * 4 + j] = -1;
            }
        } else {
#pragma unroll
            for (int j = 0; j < 4; ++j) {
                int e = ebase + j;
                if (e < E) {
                    int dj = dst[e];
                    if ((unsigned)dj < (unsigned)N) {
                        sd[l * 4 + j] = dj; ss[l * 4 + j] = src[e];
                        atomicAdd(&lc[dj >> BSHIFT], 1);
                    } else sd[l * 4 + j] = -1;
                } else sd[l * 4 + j] = -1;
            }
        }
    }
    __syncthreads();
    for (int i = threadIdx.x; i < nbuck; i += 256) {
        int c = lc[i];
        gb[i] = c ? atomicAdd(&bcur[i], c) : 0;
        lc[i] = 0;
    }
    __syncthreads();
#pragma unroll
    for (int k = 0; k < 4; ++k) {
        int l = k * 256 + threadIdx.x;
#pragma unroll
        for (int j = 0; j < 4; ++j) {
            int dj = sd[l * 4 + j];
            if (dj >= 0) {
                int b = dj >> BSHIFT;
                int idx = atomicAdd(&lc[b], 1);
                csrbuf[gb[b] + idx] = (ss[l * 4 + j] << BSHIFT) | (dj & BMASK);
            }
        }
    }
}

// ---------------- build step 4: per-bucket (stash in LDS, in-place scatter), writes row_off + dinv ----------------

__global__ __launch_bounds__(256) void k_bucket(int* __restrict__ csrbuf, const int* __restrict__ bbase,
                                                const int* __restrict__ bcnt, int* __restrict__ row_off,
                                                float* __restrict__ dinv, int N) {
    __shared__ int stash[DCAP];
    __shared__ int h[128], off[128], cur[128];
    int b = blockIdx.x;
    int rbase = bbase[b];
    int rs = bcnt[b]; if (rs > DCAP) rs = DCAP;
    int d0 = b << BSHIFT;
    int nloc = min(128, N - d0);
    if (threadIdx.x < 128) h[threadIdx.x] = 0;
    for (int i = threadIdx.x; i < rs; i += 256) stash[i] = csrbuf[rbase + i];
    __syncthreads();
    for (int i = threadIdx.x; i < rs; i += 256) atomicAdd(&h[stash[i] & BMASK], 1);
    __syncthreads();
    if (threadIdx.x < 128) off[threadIdx.x] = h[threadIdx.x];
    __syncthreads();
    for (int o = 1; o < 128; o <<= 1) {
        int t = 0;
        if (threadIdx.x < 128 && (int)threadIdx.x >= o) t = off[threadIdx.x - o];
        __syncthreads();
        if (threadIdx.x < 128) off[threadIdx.x] += t;
        __syncthreads();
    }
    if (threadIdx.x < 128) {
        int ex = off[threadIdx.x] - h[threadIdx.x];   // exclusive prefix
        cur[threadIdx.x] = ex;
        if ((int)threadIdx.x < nloc) {
            row_off[d0 + threadIdx.x] = rbase + ex;
            dinv[d0 + threadIdx.x] = rsqrtf((float)(h[threadIdx.x] + 1));  // +1 self-loop
        }
    }
    __syncthreads();
    for (int i = threadIdx.x; i < rs; i += 256) {
        int v = stash[i];
        int p = atomicAdd(&cur[v & BMASK], 1);
        csrbuf[rbase + p] = v >> BSHIFT;
    }
}

// xs_h[v] = fp16( dinv[v] * x[v] ), padded to 8 halves = 16 B/row
__global__ __launch_bounds__(256) void k_xs(const float* __restrict__ x, const float* __restrict__ dinv,
                                            uint4* __restrict__ xs_h, int N) {
    int v = blockIdx.x * blockDim.x + threadIdx.x;
    if (v < N) {
        float w = dinv[v];
        const float* xp = x + (size_t)v * 5;
        __half hs[8];
#pragma unroll
        for (int k = 0; k < 5; ++k) hs[k] = __float2half(w * xp[k]);
        hs[5] = hs[6] = hs[7] = __float2half(0.f);
        xs_h[v] = *reinterpret_cast<uint4*>(hs);
    }
}

// ---------------- Layer 1: 4-lane team per node; each lane a different edge; 2-level reduce; 5->32 matmul ----------------

__global__ __launch_bounds__(256) void k_agg1(const uint4* __restrict__ xs_h, const int* __restrict__ csr,
                                              const int* __restrict__ row_off, const float* __restrict__ dinv,
                                              const float* __restrict__ W1, const float* __restrict__ b1,
                                              float* __restrict__ out, float* __restrict__ sum, float* __restrict__ sq,
                                              int N) {
    __shared__ float W1s[160], b1s[32];
    __shared__ float lssum[128], lssq[128];
    for (int i = threadIdx.x; i < 160; i += 256) W1s[i] = W1[i];
    if (threadIdx.x < 32) b1s[threadIdx.x] = b1[threadIdx.x];
    __syncthreads();
    int lane = threadIdx.x & 63;
    int q = lane & 3;
    int team = (blockIdx.x * blockDim.x + threadIdx.x) >> 2;
    int nteams = (gridDim.x * blockDim.x) >> 2;
    float ls[8], lq[8];
#pragma unroll
    for (int j = 0; j < 8; ++j) { ls[j] = 0.f; lq[j] = 0.f; }
    for (int v = team; v < N; v += nteams) {
        int s0 = row_off[v], s1 = row_off[v + 1];
        float a0 = 0, a1 = 0, a2 = 0, a3 = 0, a4 = 0;
        int e = s0 + q;
        for (; e + 4 < s1; e += 8) {
            uint4 ua = xs_h[csr[e]];
            uint4 ub = xs_h[csr[e + 4]];
            float2 f;
            f = h2f(ua.x); a0 += f.x; a1 += f.y;
            f = h2f(ua.y); a2 += f.x; a3 += f.y;
            f = h2f(ua.z); a4 += f.x;
            f = h2f(ub.x); a0 += f.x; a1 += f.y;
            f = h2f(ub.y); a2 += f.x; a3 += f.y;
            f = h2f(ub.z); a4 += f.x;
        }
        if (e < s1) {
            uint4 ua = xs_h[csr[e]];
            float2 f;
            f = h2f(ua.x); a0 += f.x; a1 += f.y;
            f = h2f(ua.y); a2 += f.x; a3 += f.y;
            f = h2f(ua.z); a4 += f.x;
        }
#pragma unroll
        for (int off = 1; off <= 2; off <<= 1) {
            a0 += __shfl_xor(a0, off);
            a1 += __shfl_xor(a1, off);
            a2 += __shfl_xor(a2, off);
            a3 += __shfl_xor(a3, off);
            a4 += __shfl_xor(a4, off);
        }
        float dv = dinv[v];
        uint4 uv = xs_h[v];
        float2 f0 = h2f(uv.x), f1 = h2f(uv.y), f2v = h2f(uv.z);
        float t0 = dv * (a0 + f0.x);
        float t1 = dv * (a1 + f0.y);
        float t2 = dv * (a2 + f1.x);
        float t3 = dv * (a3 + f1.y);
        float t4 = dv * (a4 + f2v.x);
        float o[8];
#pragma unroll
        for (int j = 0; j < 8; ++j) {
            int c = q * 8 + j;
            float h = b1s[c];
            h = fmaf(t0, W1s[c], h);
            h = fmaf(t1, W1s[32 + c], h);
            h = fmaf(t2, W1s[64 + c], h);
            h = fmaf(t3, W1s[96 + c], h);
            h = fmaf(t4, W1s[128 + c], h);
            o[j] = h;
            ls[j] += h; lq[j] += h * h;
        }
        float4 o0 = {o[0], o[1], o[2], o[3]};
        float4 o1 = {o[4], o[5], o[6], o[7]};
        *reinterpret_cast<float4*>(out + (size_t)v * 32 + q * 8) = o0;
        *reinterpret_cast<float4*>(out + (size_t)v * 32 + q * 8 + 4) = o1;
    }
#pragma unroll
    for (int off = 4; off <= 32; off <<= 1) {
#pragma unroll
        for (int j = 0; j < 8; ++j) { ls[j] += __shfl_xor(ls[j], off); lq[j] += __shfl_xor(lq[j], off); }
    }
    int wib = threadIdx.x >> 6;
    if (lane < 4) {
#pragma unroll
        for (int j = 0; j < 8; ++j) {
            lssum[wib * 32 + q * 8 + j] = ls[j];
            lssq[wib * 32 + q * 8 + j] = lq[j];
        }
    }
    __syncthreads();
    if (threadIdx.x < 32) {
        float s = lssum[threadIdx.x] + lssum[32 + threadIdx.x] + lssum[64 + threadIdx.x] + lssum[96 + threadIdx.x];
        float t = lssq[threadIdx.x] + lssq[32 + threadIdx.x] + lssq[64 + threadIdx.x] + lssq[96 + threadIdx.x];
        atomicAdd(&sum[threadIdx.x], s);
        atomicAdd(&sq[threadIdx.x], t);
    }
}

// ---------------- BN params ----------------

__global__ void k_bnparam(const float* __restrict__ sum, const float* __restrict__ sq,
                          const float* __restrict__ gamma, const float* __restrict__ beta,
                          float* __restrict__ aOut, float* __restrict__ dOut, float invN) {
    int c = threadIdx.x;
    if (c < 32) {
        float mean = sum[c] * invN;
        float var = fmaxf(sq[c] * invN - mean * mean, 0.f);
        float rinv = rsqrtf(var + EPSBN);
        float a = gamma[c] * rinv;
        aOut[c] = a;
        dOut[c] = beta[c] - mean * a;
    }
}

// ---------------- h2h = fp16( dinv[v] * (relu(bn1(bufIn)) @ W2) ) ----------------

__global__ __launch_bounds__(256) void k_h2(const float* __restrict__ bufIn, const float* __restrict__ W2,
                                            const float* __restrict__ a1, const float* __restrict__ d1,
                                            const float* __restrict__ dinv, __half* __restrict__ h2h, int N) {
    __shared__ float W2s[1024];
    __shared__ float rbuf[8][33];
    for (int i = threadIdx.x; i < 1024; i += 256) W2s[i] = W2[i];
    int g = threadIdx.x >> 5, c = threadIdx.x & 31;
    int v = blockIdx.x * 8 + g;
    float r = 0.f;
    if (v < N) {
        float val = bufIn[(size_t)v * 32 + c];
        r = fmaxf(fmaf(a1[c], val, d1[c]), 0.f);
    }
    __syncthreads();
    rbuf[g][c] = r;
    __syncthreads();
    if (v < N) {
        float h = 0.f;
#pragma unroll
        for (int k = 0; k < 32; ++k) h = fmaf(rbuf[g][k], W2s[k * 32 + c], h);
        h2h[(size_t)v * 32 + c] = __float2half(h * dinv[v]);
    }
}

// ---------------- Layer 2: 4-lane team per node; coalesced 64B row; NO cross-lane reduce ----------------

__global__ __launch_bounds__(256) void k_agg2(const uint4* __restrict__ h2h4, const int* __restrict__ csr,
                                              const int* __restrict__ row_off, const float* __restrict__ dinv,
                                              const float* __restrict__ b2, float* __restrict__ out,
                                              float* __restrict__ sum, float* __restrict__ sq, int N) {
    __shared__ float lssum[128], lssq[128];
    int lane = threadIdx.x & 63;
    int q = lane & 3;        // 16B slot: channels q*8 .. q*8+7
    int team = (blockIdx.x * blockDim.x + threadIdx.x) >> 2;
    int nteams = (gridDim.x * blockDim.x) >> 2;
    float bcv[8];
#pragma unroll
    for (int j = 0; j < 8; ++j) bcv[j] = b2[q * 8 + j];
    float ls[8], lq[8];
#pragma unroll
    for (int j = 0; j < 8; ++j) { ls[j] = 0.f; lq[j] = 0.f; }
    for (int v = team; v < N; v += nteams) {
        int s0 = row_off[v], s1 = row_off[v + 1];
        float acc[8];
#pragma unroll
        for (int j = 0; j < 8; ++j) acc[j] = 0.f;
        int e = s0;
        for (; e + 4 <= s1; e += 4) {
            int sA = csr[e], sB = csr[e + 1], sC = csr[e + 2], sD = csr[e + 3];
            uint4 ua = h2h4[(size_t)sA * 4 + q];
            uint4 ub = h2h4[(size_t)sB * 4 + q];
            uint4 uc = h2h4[(size_t)sC * 4 + q];
            uint4 ud = h2h4[(size_t)sD * 4 + q];
            acc8(acc, ua); acc8(acc, ub); acc8(acc, uc); acc8(acc, ud);
        }
        for (; e < s1; ++e) {
            uint4 ua = h2h4[(size_t)csr[e] * 4 + q];
            acc8(acc, ua);
        }
        float dv = dinv[v];
        uint4 uv = h2h4[(size_t)v * 4 + q];   // already dinv[v]*h2
        float hv[8];
        float2 f;
        f = h2f(uv.x); hv[0] = f.x; hv[1] = f.y;
        f = h2f(uv.y); hv[2] = f.x; hv[3] = f.y;
        f = h2f(uv.z); hv[4] = f.x; hv[5] = f.y;
        f = h2f(uv.w); hv[6] = f.x; hv[7] = f.y;
        float o[8];
#pragma unroll
        for (int j = 0; j < 8; ++j) {
            o[j] = fmaf(dv, acc[j] + hv[j], bcv[j]);
            ls[j] += o[j]; lq[j] += o[j] * o[j];
        }
        float4 o0 = {o[0], o[1], o[2], o[3]};
        float4 o1 = {o[4], o[5], o[6], o[7]};
        *reinterpret_cast<float4*>(out + (size_t)v * 32 + q * 8) = o0;
        *reinterpret_cast<float4*>(out + (size_t)v * 32 + q * 8 + 4) = o1;
    }
#pragma unroll
    for (int off = 4; off <= 32; off <<= 1) {
#pragma unroll
        for (int j = 0; j < 8; ++j) { ls[j] += __shfl_xor(ls[j], off); lq[j] += __shfl_xor(lq[j], off); }
    }
    int wib = threadIdx.x >> 6;
    if (lane < 4) {
#pragma unroll
        for (int j = 0; j < 8; ++j) {
            lssum[wib * 32 + q * 8 + j] = ls[j];
            lssq[wib * 32 + q * 8 + j] = lq[j];
        }
    }
    __syncthreads();
    if (threadIdx.x < 32) {
        float s = lssum[threadIdx.x] + lssum[32 + threadIdx.x] + lssum[64 + threadIdx.x] + lssum[96 + threadIdx.x];
        float t = lssq[threadIdx.x] + lssq[32 + threadIdx.x] + lssq[64 + threadIdx.x] + lssq[96 + threadIdx.x];
        atomicAdd(&sum[threadIdx.x], s);
        atomicAdd(&sq[threadIdx.x], t);
    }
}

// ---------------- p[v] = dinv[v] * (relu(bn2(buf[v])) @ W3) ----------------

__global__ __launch_bounds__(256) void k_h3p(const float* __restrict__ buf, const float* __restrict__ a2,
                                             const float* __restrict__ d2, const float* __restrict__ W3,
                                             const float* __restrict__ dinv, float* __restrict__ p, int N) {
    int c = threadIdx.x & 31;
    int v = blockIdx.x * 8 + (threadIdx.x >> 5);
    if (v >= N) return;
    float val = buf[(size_t)v * 32 + c];
    float r = fmaxf(fmaf(a2[c], val, d2[c]), 0.f) * W3[c];
#pragma unroll
    for (int off = 16; off >= 1; off >>= 1) r += __shfl_xor(r, off, 32);
    if (c == 0) p[v] = dinv[v] * r;
}

// ---------------- Layer 3: scalar gather-reduce ----------------

__global__ __launch_bounds__(256) void k_agg3(const float* __restrict__ p, const int* __restrict__ csr,
                                              const int* __restrict__ row_off, const float* __restrict__ dinv,
                                              const float* __restrict__ b3, float* __restrict__ out, int N) {
    int lane = threadIdx.x & 63;
    int wave = (blockIdx.x * blockDim.x + threadIdx.x) >> 6;
    int nw = (gridDim.x * blockDim.x) >> 6;
    for (int v = wave; v < N; v += nw) {
        int s0 = row_off[v], s1 = row_off[v + 1];
        float acc = 0.f;
        int e = s0 + lane;
        for (; e + 64 < s1; e += 128) acc += p[csr[e]] + p[csr[e + 64]];
        if (e < s1) acc += p[csr[e]];
#pragma unroll
        for (int off = 32; off >= 1; off >>= 1) acc += __shfl_xor(acc, off);
        if (lane == 0) out[v] = fmaf(dinv[v], acc + p[v], b3[0]);
    }
}

// ---------------- launch ----------------

extern "C" void kernel_launch(void* const* d_in, const int* in_sizes, int n_in,
                              void* d_out, int out_size, void* d_ws, size_t ws_size,
                              hipStream_t stream) {
    const float* x      = (const float*)d_in[0];
    const int*   ei     = (const int*)d_in[1];
    const float* W1     = (const float*)d_in[2];
    const float* b1     = (const float*)d_in[3];
    const float* gamma1 = (const float*)d_in[4];
    const float* beta1  = (const float*)d_in[5];
    const float* W2     = (const float*)d_in[6];
    const float* b2     = (const float*)d_in[7];
    const float* gamma2 = (const float*)d_in[8];
    const float* beta2  = (const float*)d_in[9];
    const float* W3     = (const float*)d_in[10];
    const float* b3     = (const float*)d_in[11];

    int N = out_size;             // 100000 nodes (<= 131072 for LDS hists)
    int E = in_sizes[1] / 2;      // 6400000 edges
    const int* srcp = ei;
    const int* dstp = ei + E;
    int nbuck = (N + BMASK) >> BSHIFT;   // 782

    char* w = (char*)d_ws;
    int*    csr     = (int*)w;         w += alignup((size_t)E * 4);     // doubles as packed-pair buffer
    int*    row_off = (int*)w;         w += alignup((size_t)(N + 1) * 4);
    float*  dinv    = (float*)w;       w += alignup((size_t)N * 4);
    uint4*  xs_h    = (uint4*)w;       w += alignup((size_t)N * 16);
    __half* h2h     = (__half*)w;      w += alignup((size_t)N * 32 * 2);
    float*  buf     = (float*)w;       w += alignup((size_t)N * 32 * 4);
    float*  pbuf    = (float*)w;       w += alignup((size_t)N * 4);
    float*  stats   = (float*)w;       w += alignup(256 * 4);
    int*    bcnt    = (int*)w;         w += alignup(1024 * 4);
    int*    bbase   = (int*)w;         w += alignup(1024 * 4);
    int*    bcur    = (int*)w;         w += alignup(1024 * 4);

    float* sum1 = stats, *sq1 = stats + 32, *sum2 = stats + 64, *sq2 = stats + 96;
    float* a1 = stats + 128, *d1 = stats + 160, *a2 = stats + 192, *d2 = stats + 224;

    (void)hipMemsetAsync(bcnt, 0, 1024 * 4, stream);
    (void)hipMemsetAsync(stats, 0, 128 * 4, stream);

    k_bcount<<<1024, 256, 0, stream>>>(dstp, bcnt, E, N, nbuck);
    k_bscan<<<1, 64, 0, stream>>>(bcnt, bbase, bcur, row_off, nbuck, N);
    k_bin<<<(E + CHUNK - 1) / CHUNK, 256, 0, stream>>>(srcp, dstp, bcur, csr, E, N, nbuck);
    k_bucket<<<nbuck, 256, 0, stream>>>(csr, bbase, bcnt, row_off, dinv, N);
    k_xs<<<(N + 255) / 256, 256, 0, stream>>>(x, dinv, xs_h, N);

    float invN = 1.0f / (float)N;

    k_agg1<<<2048, 256, 0, stream>>>(xs_h, csr, row_off, dinv, W1, b1, buf, sum1, sq1, N);
    k_bnparam<<<1, 32, 0, stream>>>(sum1, sq1, gamma1, beta1, a1, d1, invN);
    k_h2<<<(N + 7) / 8, 256, 0, stream>>>(buf, W2, a1, d1, dinv, h2h, N);
    k_agg2<<<2048, 256, 0, stream>>>((const uint4*)h2h, csr, row_off, dinv, b2, buf, sum2, sq2, N);
    k_bnparam<<<1, 32, 0, stream>>>(sum2, sq2, gamma2, beta2, a2, d2, invN);
    k_h3p<<<(N + 7) / 8, 256, 0, stream>>>(buf, a2, d2, W3, dinv, pbuf, N);
    k_agg3<<<2048, 256, 0, stream>>>(pbuf, csr, row_off, dinv, b3, (float*)d_out, N);
}